// Round 6
// baseline (1189.077 us; speedup 1.0000x reference)
//
#include <hip/hip_runtime.h>
#include <hip/hip_fp16.h>

#define NN 50000
#define NE 800000
#define HIDD 128
#define FEAT_E 16
#define NGRAPH 8
#define CAP 64

typedef __attribute__((ext_vector_type(2))) _Float16 half2_t;
typedef __attribute__((ext_vector_type(4))) _Float16 half4_t;
typedef __attribute__((ext_vector_type(8))) _Float16 half8_t;
typedef __attribute__((ext_vector_type(4))) float floatx4;

// Channel permutation used for xl/xr/h tables: position p holds original
// channel c(p) = 16*(p&7) + (p>>3); inverse p(c) = 8*(c&15) + (c>>4).
// Chosen so that MFMA C/D fragments (col=lane&15, row=quad*4+i) see each
// lane's 8 channels as ONE contiguous half8 at offset l16*8.

// ---- order-preserving float<->uint encoding for atomicMax on floats ----
__device__ __forceinline__ unsigned int fenc(float f) {
  unsigned int u = __float_as_uint(f);
  return (u & 0x80000000u) ? ~u : (u | 0x80000000u);
}
__device__ __forceinline__ float fdec(unsigned int u) {
  if (u == 0u) return 0.0f;
  float f = (u & 0x80000000u) ? __uint_as_float(u & 0x7fffffffu)
                              : __uint_as_float(~u);
  return __builtin_isfinite(f) ? f : 0.0f;
}

__device__ __forceinline__ half2_t h2shfl_xor(half2_t v, int m) {
  int iv = __builtin_bit_cast(int, v);
  iv = __shfl_xor(iv, m, 16);
  return __builtin_bit_cast(half2_t, iv);
}

// em MFMA: D[edge][ch] = ea @ We + C, K=16. Prefer the legacy K=16 opcode;
// fall back to K=32 with a consistent A/B k-slot relabeling (zeros elsewhere).
__device__ __forceinline__ floatx4 em_mfma(half4_t a4, half4_t b4, floatx4 c) {
#if __has_builtin(__builtin_amdgcn_mfma_f32_16x16x16f16)
  return __builtin_amdgcn_mfma_f32_16x16x16f16(a4, b4, c, 0, 0, 0);
#else
  const _Float16 z = (_Float16)0.f;
  half8_t a8 = {a4[0], a4[1], a4[2], a4[3], z, z, z, z};
  half8_t b8 = {b4[0], b4[1], b4[2], b4[3], z, z, z, z};
  return __builtin_amdgcn_mfma_f32_16x16x32_f16(a8, b8, c, 0, 0, 0);
#endif
}

// ---- prep: wtg[which(2)][oc(128)][col(128)] fp16, col = k ^ ((oc&7)<<3)
// (bank swizzle). For layer 2 (perm=1) row p holds W[c(p)][oc] so the GEMM
// against permuted-layout h is correct.
__global__ void prep_wt_k(const float* __restrict__ Wl, const float* __restrict__ Wr,
                          _Float16* __restrict__ wtg, int perm) {
  const int oc = blockIdx.x & 127;
  const int which = blockIdx.x >> 7;
  const int p = threadIdx.x;  // row position 0..127
  const float* W = which ? Wr : Wl;
  const int srck = perm ? (16 * (p & 7) + (p >> 3)) : p;
  const int col = p ^ ((oc & 7) << 3);
  wtg[(which * 128 + oc) * 128 + col] = (_Float16)W[srck * 128 + oc];
}

// ---- A-fragment loaders (fp32 input layer 1, fp16 layer 2) ----
__device__ __forceinline__ half8_t load_a8(const _Float16* p) {
  return *(const half8_t*)p;
}
__device__ __forceinline__ half8_t load_a8(const float* p) {
  const float4 f0 = *(const float4*)p;
  const float4 f1 = *(const float4*)(p + 4);
  return (half8_t){(_Float16)f0.x, (_Float16)f0.y, (_Float16)f0.z, (_Float16)f0.w,
                   (_Float16)f1.x, (_Float16)f1.y, (_Float16)f1.z, (_Float16)f1.w};
}

// ---- node linear via MFMA, LDS-staged swizzled weights ----
// grid (ceil(NN/64), 2): blockIdx.y = 0 -> xl (Wl), 1 -> xr (Wr).
// block 256 = 4 waves; wave = 16 nodes x 128 outs (8 tiles, 32 acc VGPR).
// Output written in PERMUTED channel layout -> one half8 store per row.
template <typename TIN>
__global__ __launch_bounds__(256) void node_linear_mfma_k(
    const TIN* __restrict__ x, const _Float16* __restrict__ wtg,
    const float* __restrict__ bl, const float* __restrict__ br,
    _Float16* __restrict__ xl16, _Float16* __restrict__ xr16) {
  __shared__ _Float16 wt[128 * 128];  // 32 KB
  const int tid = threadIdx.x;
  const int which = blockIdx.y;
  const _Float16* wsrc = wtg + which * (128 * 128);
  const float* bias128 = which ? br : bl;
  _Float16* out = which ? xr16 : xl16;
  {
    const half8_t* src = (const half8_t*)wsrc;
    half8_t* dstl = (half8_t*)wt;
#pragma unroll
    for (int it = 0; it < 8; ++it)
      dstl[it * 256 + tid] = src[it * 256 + tid];
  }
  __syncthreads();

  const int wv = tid >> 6, lane = tid & 63;
  const int arow = lane & 15, kq = lane >> 4;
  const int nbase = blockIdx.x * 64 + wv * 16;
  int nload = nbase + arow;
  if (nload >= NN) nload = NN - 1;
  floatx4 acc[8];
#pragma unroll
  for (int t = 0; t < 8; ++t) acc[t] = (floatx4){0.f, 0.f, 0.f, 0.f};
#pragma unroll
  for (int kb = 0; kb < 4; ++kb) {
    const half8_t a = load_a8(x + (size_t)nload * 128 + kb * 32 + kq * 8);
    const int colbase = (kb * 32 + kq * 8) ^ ((arow & 7) << 3);
#pragma unroll
    for (int t = 0; t < 8; ++t) {
      const half8_t b = *(const half8_t*)&wt[(t * 16 + arow) * 128 + colbase];
      acc[t] = __builtin_amdgcn_mfma_f32_16x16x32_f16(a, b, acc[t], 0, 0, 0);
    }
  }
  // lane holds oc = t*16+arow for nodes nbase+kq*4+i.
  // perm position p(oc) = 8*(oc&15)+(oc>>4) = arow*8 + t -> contiguous half8.
  float bv[8];
#pragma unroll
  for (int t = 0; t < 8; ++t) bv[t] = bias128[t * 16 + arow];
#pragma unroll
  for (int i = 0; i < 4; ++i) {
    const int n = nbase + kq * 4 + i;
    if (n < NN) {
      half8_t v;
#pragma unroll
      for (int t = 0; t < 8; ++t) v[t] = (_Float16)(acc[t][i] + bv[t]);
      *(half8_t*)(out + (size_t)n * 128 + arow * 8) = v;
    }
  }
}

// ---- build: in-edge CSR (src,eidx int2) + fp16 edge-attr copy ----
__global__ void build_k(const int* __restrict__ src, const int* __restrict__ dst,
                        const float* __restrict__ eattr,
                        int* __restrict__ cnt, int2* __restrict__ bpair,
                        _Float16* __restrict__ eatt16) {
  const int e = blockIdx.x * blockDim.x + threadIdx.x;
  if (e >= NE) return;
  const float4* ea = (const float4*)(eattr + (size_t)e * FEAT_E);
  const float4 a0 = ea[0], a1 = ea[1], a2 = ea[2], a3 = ea[3];
  half8_t h0 = {(_Float16)a0.x, (_Float16)a0.y, (_Float16)a0.z, (_Float16)a0.w,
                (_Float16)a1.x, (_Float16)a1.y, (_Float16)a1.z, (_Float16)a1.w};
  half8_t h1 = {(_Float16)a2.x, (_Float16)a2.y, (_Float16)a2.z, (_Float16)a2.w,
                (_Float16)a3.x, (_Float16)a3.y, (_Float16)a3.z, (_Float16)a3.w};
  half8_t* eo = (half8_t*)(eatt16 + (size_t)e * FEAT_E);
  eo[0] = h0; eo[1] = h1;
  const int d = dst[e];
  const int pos = atomicAdd(&cnt[d], 1);
  if (pos < CAP) bpair[(size_t)d * CAP + pos] = make_int2(src[e], e);
}

// ---- FUSED per-node GATv2, MFMA edition ----
// block 256 = 4 waves; wave per destination node; 16 edges per iteration.
// Lane (kq = lane>>4, l16 = lane&15): channels {16t+l16, t<8} (permuted
// layout = contiguous half8), edges kq*4+i.
// m = xl+xr+em computed as ONE MFMA group: A = ea (16 edges x 16 f),
// B = We frags (registers), C preloaded with xl+xr. No max-shift (logits
// O(1), softmax shift-invariant; rounds 1-5 absmax 0.0).
__global__ __launch_bounds__(256) void node_gat_fused_k(
    const _Float16* __restrict__ xl16, const _Float16* __restrict__ xr16,
    const _Float16* __restrict__ eatt16,
    const int2* __restrict__ bpair, const int* __restrict__ cnt,
    const float* __restrict__ We, const float* __restrict__ att,
    const float* __restrict__ bias, _Float16* __restrict__ hout) {
  const int tid = threadIdx.x;
  const int wave = tid >> 6, lane = tid & 63;
  const int l16 = lane & 15, kq = lane >> 4;
  const int d = blockIdx.x * 4 + wave;  // grid = NN/4 exactly

  // loop-invariant fragments: Bf[t][j] = We[kq*4+j][16t+l16]
  half4_t Bf[8];
#pragma unroll
  for (int t = 0; t < 8; ++t) {
#pragma unroll
    for (int j = 0; j < 4; ++j)
      Bf[t][j] = (_Float16)We[(kq * 4 + j) * 128 + 16 * t + l16];
  }
  float attR[8], xrf[8];
  const half8_t xrh = *(const half8_t*)(xr16 + (size_t)d * 128 + l16 * 8);
#pragma unroll
  for (int t = 0; t < 8; ++t) {
    attR[t] = att[16 * t + l16];
    xrf[t] = (float)xrh[t];
  }

  int deg = cnt[d];
  deg = deg < CAP ? deg : CAP;
  const int2* bp = bpair + (size_t)d * CAP;

  float acc[8] = {0.f, 0.f, 0.f, 0.f, 0.f, 0.f, 0.f, 0.f};
  float den[4] = {0.f, 0.f, 0.f, 0.f};

  for (int jb = 0; jb < deg; jb += 16) {
    const int myE = jb + l16;
    const int ridx = myE < CAP ? myE : CAP - 1;
    const int2 pr = bp[ridx];
    const bool okl = myE < deg;
    const int ey = okl ? pr.y : 0;   // clamp: garbage indices beyond deg
    const int sxv = okl ? pr.x : 0;
    // A-frag: ea[edge=l16][f=kq*4+j]
    const half4_t a4 = *(const half4_t*)(eatt16 + (size_t)(unsigned)ey * FEAT_E + kq * 4);
    // src ids of this kq-group's 4 edges (from lanes kq*4+i of own segment)
    const int s0 = __shfl(sxv, kq * 4 + 0, 16);
    const int s1 = __shfl(sxv, kq * 4 + 1, 16);
    const int s2 = __shfl(sxv, kq * 4 + 2, 16);
    const int s3 = __shfl(sxv, kq * 4 + 3, 16);
    const half8_t xl0 = *(const half8_t*)(xl16 + (size_t)(unsigned)s0 * 128 + l16 * 8);
    const half8_t xl1 = *(const half8_t*)(xl16 + (size_t)(unsigned)s1 * 128 + l16 * 8);
    const half8_t xl2 = *(const half8_t*)(xl16 + (size_t)(unsigned)s2 * 128 + l16 * 8);
    const half8_t xl3 = *(const half8_t*)(xl16 + (size_t)(unsigned)s3 * 128 + l16 * 8);
    // C init = xl + xr (fp32); MFMA adds em -> c = m pre-activation
    floatx4 c[8];
#pragma unroll
    for (int t = 0; t < 8; ++t) {
      c[t][0] = (float)xl0[t] + xrf[t];
      c[t][1] = (float)xl1[t] + xrf[t];
      c[t][2] = (float)xl2[t] + xrf[t];
      c[t][3] = (float)xl3[t] + xrf[t];
    }
#pragma unroll
    for (int t = 0; t < 8; ++t) c[t] = em_mfma(a4, Bf[t], c[t]);
    // leaky + per-head att partials (edge i, head h = t>>1)
    float part[4][4];
#pragma unroll
    for (int i = 0; i < 4; ++i)
      part[i][0] = part[i][1] = part[i][2] = part[i][3] = 0.f;
#pragma unroll
    for (int t = 0; t < 8; ++t) {
#pragma unroll
      for (int i = 0; i < 4; ++i) {
        const float m = c[t][i];
        const float lk = fmaxf(m, 0.2f * m);
        part[i][t >> 1] = fmaf(lk, attR[t], part[i][t >> 1]);
      }
    }
    // pack per-edge head pairs to fp16, butterfly-sum over the 16 lanes
    half2_t pk[8];
#pragma unroll
    for (int i = 0; i < 4; ++i) {
      pk[i * 2]     = (half2_t){(_Float16)part[i][0], (_Float16)part[i][1]};
      pk[i * 2 + 1] = (half2_t){(_Float16)part[i][2], (_Float16)part[i][3]};
    }
#pragma unroll
    for (int mask = 1; mask <= 8; mask <<= 1) {
#pragma unroll
      for (int r = 0; r < 8; ++r) pk[r] += h2shfl_xor(pk[r], mask);
    }
    // exp + tail mask + denominators + weighted aggregation
#define AGG(I, XLH)                                                       \
    {                                                                     \
      const bool ev = (jb + kq * 4 + I) < deg;                            \
      const float w0 = ev ? __expf((float)pk[I * 2][0]) : 0.f;            \
      const float w1 = ev ? __expf((float)pk[I * 2][1]) : 0.f;            \
      const float w2 = ev ? __expf((float)pk[I * 2 + 1][0]) : 0.f;        \
      const float w3 = ev ? __expf((float)pk[I * 2 + 1][1]) : 0.f;        \
      den[0] += w0; den[1] += w1; den[2] += w2; den[3] += w3;             \
      acc[0] = fmaf(w0, (float)(XLH)[0], acc[0]);                         \
      acc[1] = fmaf(w0, (float)(XLH)[1], acc[1]);                         \
      acc[2] = fmaf(w1, (float)(XLH)[2], acc[2]);                         \
      acc[3] = fmaf(w1, (float)(XLH)[3], acc[3]);                         \
      acc[4] = fmaf(w2, (float)(XLH)[4], acc[4]);                         \
      acc[5] = fmaf(w2, (float)(XLH)[5], acc[5]);                         \
      acc[6] = fmaf(w3, (float)(XLH)[6], acc[6]);                         \
      acc[7] = fmaf(w3, (float)(XLH)[7], acc[7]);                         \
    }
    AGG(0, xl0) AGG(1, xl1) AGG(2, xl2) AGG(3, xl3)
#undef AGG
  }
  // merge the 4 kq-groups (lane bits 4,5)
#pragma unroll
  for (int t = 0; t < 8; ++t) {
    acc[t] += __shfl_xor(acc[t], 16);
    acc[t] += __shfl_xor(acc[t], 32);
  }
#pragma unroll
  for (int h = 0; h < 4; ++h) {
    den[h] += __shfl_xor(den[h], 16);
    den[h] += __shfl_xor(den[h], 32);
  }
  if (kq == 0) {
    float inv[4];
#pragma unroll
    for (int h = 0; h < 4; ++h) inv[h] = 1.f / (den[h] + 1e-16f);
    half8_t ho;
#pragma unroll
    for (int t = 0; t < 8; ++t) {
      float o = fmaf(acc[t], inv[t >> 1], bias[16 * t + l16]);
      o = o > 0.f ? o : expm1f(o);  // ELU
      ho[t] = (_Float16)o;
    }
    *(half8_t*)(hout + (size_t)d * 128 + l16 * 8) = ho;  // permuted layout
  }
}

// ---- graph pooling (fp16 h, permuted layout -> map position to channel) ----
__global__ void pool_k(const _Float16* __restrict__ h, const int* __restrict__ batch,
                       float* __restrict__ gsum, unsigned int* __restrict__ gmax,
                       float* __restrict__ gcnt) {
  __shared__ float ssum[NGRAPH][HIDD];
  __shared__ float smax[NGRAPH][HIDD];
  __shared__ float scnt[NGRAPH];
  const int t = threadIdx.x;
  const int cmap = 16 * (t & 7) + (t >> 3);  // original channel of position t
#pragma unroll
  for (int g = 0; g < NGRAPH; ++g) {
    ssum[g][t] = 0.f;
    smax[g][t] = -3.0e38f;
  }
  if (t < NGRAPH) scnt[t] = 0.f;
  __syncthreads();
  const int n0 = blockIdx.x * 64;
  const int nEnd = (n0 + 64 < NN) ? (n0 + 64) : NN;
  unsigned int seen = 0;
  for (int n = n0; n < nEnd; ++n) {
    const int g = batch[n];
    seen |= 1u << g;
    const float v = (float)h[(size_t)n * HIDD + t];
    ssum[g][t] += v;
    smax[g][t] = fmaxf(smax[g][t], v);
    if (t == 0) scnt[g] += 1.f;
  }
  __syncthreads();
  for (int g = 0; g < NGRAPH; ++g) {
    if (seen & (1u << g)) {
      atomicAdd(&gsum[g * HIDD + cmap], ssum[g][t]);
      atomicMax(&gmax[g * HIDD + cmap], fenc(smax[g][t]));
      if (t == 0) atomicAdd(&gcnt[g], scnt[g]);
    }
  }
}

// ---- FC head (original channel space) ----
__global__ void head_k(const float* __restrict__ suma, const unsigned int* __restrict__ maxa,
                       const float* __restrict__ cnta,
                       const float* __restrict__ sumb, const unsigned int* __restrict__ maxb,
                       const float* __restrict__ cntb,
                       const float* __restrict__ Wf1, const float* __restrict__ bf1,
                       const float* __restrict__ Wf2, const float* __restrict__ bf2,
                       float* __restrict__ out) {
  __shared__ float c[4 * HIDD];
  __shared__ float red[HIDD];
  const int g = blockIdx.x, t = threadIdx.x;  // 128 threads
  const float ca = fmaxf(cnta[g], 1.f), cb = fmaxf(cntb[g], 1.f);
  c[t]            = suma[g * HIDD + t] / ca;
  c[HIDD + t]     = fdec(maxa[g * HIDD + t]);
  c[2 * HIDD + t] = sumb[g * HIDD + t] / cb;
  c[3 * HIDD + t] = fdec(maxb[g * HIDD + t]);
  __syncthreads();
  float acc = bf1[t];
  for (int i = 0; i < 4 * HIDD; ++i)
    acc = fmaf(c[i], Wf1[(size_t)i * HIDD + t], acc);
  acc = fmaxf(acc, 0.f);
  red[t] = acc * Wf2[t];
  __syncthreads();
  for (int s2 = 64; s2 > 0; s2 >>= 1) {
    if (t < s2) red[t] += red[t + s2];
    __syncthreads();
  }
  if (t == 0) out[g] = 1.f / (1.f + expf(-(red[0] + bf2[0])));
}

extern "C" void kernel_launch(void* const* d_in, const int* in_sizes, int n_in,
                              void* d_out, int out_size, void* d_ws, size_t ws_size,
                              hipStream_t stream) {
  (void)in_sizes; (void)n_in; (void)out_size; (void)ws_size;
  const float* xA    = (const float*)d_in[0];
  const int*   eiA   = (const int*)  d_in[1];
  const float* eaA   = (const float*)d_in[2];
  const int*   batA  = (const int*)  d_in[3];
  const float* xB    = (const float*)d_in[4];
  const int*   eiB   = (const int*)  d_in[5];
  const float* eaB   = (const float*)d_in[6];
  const int*   batB  = (const int*)  d_in[7];
  const float* W1l   = (const float*)d_in[8];
  const float* b1l   = (const float*)d_in[9];
  const float* W1r   = (const float*)d_in[10];
  const float* b1r   = (const float*)d_in[11];
  const float* W1e   = (const float*)d_in[12];
  const float* att1  = (const float*)d_in[13];
  const float* bias1 = (const float*)d_in[14];
  const float* W2l   = (const float*)d_in[15];
  const float* b2l   = (const float*)d_in[16];
  const float* W2r   = (const float*)d_in[17];
  const float* b2r   = (const float*)d_in[18];
  const float* W2e   = (const float*)d_in[19];
  const float* att2  = (const float*)d_in[20];
  const float* bias2 = (const float*)d_in[21];
  const float* Wf1   = (const float*)d_in[22];
  const float* bf1   = (const float*)d_in[23];
  const float* Wf2   = (const float*)d_in[24];
  const float* bf2   = (const float*)d_in[25];

  char* ws = (char*)d_ws;
  size_t off = 0;
  auto alloc = [&](size_t bytes) -> void* {
    void* p = ws + off;
    off += (bytes + 255) & ~(size_t)255;
    return p;
  };
  _Float16* h16    = (_Float16*)alloc((size_t)NN * HIDD * 2);
  _Float16* xl16   = (_Float16*)alloc((size_t)NN * HIDD * 2);
  _Float16* xr16   = (_Float16*)alloc((size_t)NN * HIDD * 2);
  int2*     bpair  = (int2*)    alloc((size_t)NN * CAP * 8);
  _Float16* eatt16 = (_Float16*)alloc((size_t)NE * FEAT_E * 2);
  int*      cnt    = (int*)     alloc((size_t)NN * 4);
  _Float16* wtg1   = (_Float16*)alloc(2 * 128 * 128 * 2);
  _Float16* wtg2   = (_Float16*)alloc(2 * 128 * 128 * 2);
  const size_t poolStart = off;
  float*        psumA = (float*)alloc(NGRAPH * HIDD * 4);
  unsigned int* pmaxA = (unsigned int*)alloc(NGRAPH * HIDD * 4);
  float*        pcntA = (float*)alloc(NGRAPH * 4);
  float*        psumB = (float*)alloc(NGRAPH * HIDD * 4);
  unsigned int* pmaxB = (unsigned int*)alloc(NGRAPH * HIDD * 4);
  float*        pcntB = (float*)alloc(NGRAPH * 4);
  const size_t poolBytes = off - poolStart;

  const float* xs[2]   = {xA, xB};
  const int*   eis[2]  = {eiA, eiB};
  const float* eas[2]  = {eaA, eaB};
  const int*   bats[2] = {batA, batB};
  float*        psums[2] = {psumA, psumB};
  unsigned int* pmaxs[2] = {pmaxA, pmaxB};
  float*        pcnts[2] = {pcntA, pcntB};

  hipMemsetAsync(psumA, 0, poolBytes, stream);  // 0 == encoded -inf for max
  prep_wt_k<<<256, 128, 0, stream>>>(W1l, W1r, wtg1, 0);  // layer 1: no perm
  prep_wt_k<<<256, 128, 0, stream>>>(W2l, W2r, wtg2, 1);  // layer 2: k-perm

  for (int g = 0; g < 2; ++g) {
    const int* src = eis[g];
    const int* dst = eis[g] + NE;
    hipMemsetAsync(cnt, 0, (size_t)NN * 4, stream);
    build_k<<<NE / 256, 256, 0, stream>>>(src, dst, eas[g], cnt, bpair, eatt16);
    // layer 1 (fp32 x input, standard layout)
    node_linear_mfma_k<float><<<dim3((NN + 63) / 64, 2), 256, 0, stream>>>(
        xs[g], wtg1, b1l, b1r, xl16, xr16);
    node_gat_fused_k<<<NN / 4, 256, 0, stream>>>(xl16, xr16, eatt16, bpair, cnt,
                                                 W1e, att1, bias1, h16);
    // layer 2 (fp16 h input, permuted layout matched by wtg2 row-perm)
    node_linear_mfma_k<_Float16><<<dim3((NN + 63) / 64, 2), 256, 0, stream>>>(
        h16, wtg2, b2l, b2r, xl16, xr16);
    node_gat_fused_k<<<NN / 4, 256, 0, stream>>>(xl16, xr16, eatt16, bpair, cnt,
                                                 W2e, att2, bias2, h16);
    // pooling (permuted h -> channel map inside)
    pool_k<<<(NN + 63) / 64, 128, 0, stream>>>(h16, bats[g], psums[g], pmaxs[g], pcnts[g]);
  }
  head_k<<<NGRAPH, 128, 0, stream>>>(psumA, pmaxA, pcntA, psumB, pmaxB, pcntB,
                                     Wf1, bf1, Wf2, bf2, (float*)d_out);
}

// Round 7
// 929.471 us; speedup vs baseline: 1.2793x; 1.2793x over previous
//
#include <hip/hip_runtime.h>
#include <hip/hip_fp16.h>

#define NN 50000
#define NE 800000
#define HIDD 128
#define FEAT_E 16
#define NGRAPH 8
#define CAP 64
#define NPW 8  // nodes processed serially per wave (prologue amortization)

typedef __attribute__((ext_vector_type(2))) _Float16 half2_t;
typedef __attribute__((ext_vector_type(8))) _Float16 half8_t;
typedef __attribute__((ext_vector_type(4))) float floatx4;

// Channel permutation for xl/xr/h tables: position p holds original channel
// c(p) = 16*(p&7) + (p>>3). Chosen so MFMA C/D fragments (col=lane&15,
// row=quad*4+i) store as ONE contiguous half8 per lane (node_linear epilogue),
// at the cost of each lane's 8 positions spanning all 4 heads (2 per head)
// in the fused kernel -> per-head packed butterfly there.

// ---- order-preserving float<->uint encoding for atomicMax on floats ----
__device__ __forceinline__ unsigned int fenc(float f) {
  unsigned int u = __float_as_uint(f);
  return (u & 0x80000000u) ? ~u : (u | 0x80000000u);
}
__device__ __forceinline__ float fdec(unsigned int u) {
  if (u == 0u) return 0.0f;
  float f = (u & 0x80000000u) ? __uint_as_float(u & 0x7fffffffu)
                              : __uint_as_float(~u);
  return __builtin_isfinite(f) ? f : 0.0f;
}

__device__ __forceinline__ half8_t splat8(_Float16 v) {
  return (half8_t){v, v, v, v, v, v, v, v};
}
__device__ __forceinline__ half8_t hmax8(half8_t a, half8_t b) {
#if __has_builtin(__builtin_elementwise_max)
  return __builtin_elementwise_max(a, b);
#else
  half8_t r;
#pragma unroll
  for (int i = 0; i < 8; ++i) r[i] = a[i] > b[i] ? a[i] : b[i];
  return r;
#endif
}
__device__ __forceinline__ half2_t h2shfl_xor(half2_t v, int m) {
  int iv = __builtin_bit_cast(int, v);
  iv = __shfl_xor(iv, m, 16);
  return __builtin_bit_cast(half2_t, iv);
}
__device__ __forceinline__ float fdot2h(half2_t a, half2_t b, float c) {
#if __has_builtin(__builtin_amdgcn_fdot2)
  return __builtin_amdgcn_fdot2(a, b, c, false);
#else
  return c + (float)a[0] * (float)b[0] + (float)a[1] * (float)b[1];
#endif
}

// ---- prep: wtg[which(2)][oc(128)][col(128)] fp16, col = k ^ ((oc&7)<<3)
// (bank swizzle). perm=1: row p holds W[c(p)][oc] (layer 2 reads permuted h).
__global__ void prep_wt_k(const float* __restrict__ Wl, const float* __restrict__ Wr,
                          _Float16* __restrict__ wtg, int perm) {
  const int oc = blockIdx.x & 127;
  const int which = blockIdx.x >> 7;
  const int p = threadIdx.x;  // row position 0..127
  const float* W = which ? Wr : Wl;
  const int srck = perm ? (16 * (p & 7) + (p >> 3)) : p;
  const int col = p ^ ((oc & 7) << 3);
  wtg[(which * 128 + oc) * 128 + col] = (_Float16)W[srck * 128 + oc];
}

// ---- A-fragment loaders (fp32 input layer 1, fp16 layer 2) ----
__device__ __forceinline__ half8_t load_a8(const _Float16* p) {
  return *(const half8_t*)p;
}
__device__ __forceinline__ half8_t load_a8(const float* p) {
  const float4 f0 = *(const float4*)p;
  const float4 f1 = *(const float4*)(p + 4);
  return (half8_t){(_Float16)f0.x, (_Float16)f0.y, (_Float16)f0.z, (_Float16)f0.w,
                   (_Float16)f1.x, (_Float16)f1.y, (_Float16)f1.z, (_Float16)f1.w};
}

// ---- node linear via MFMA, LDS-staged swizzled weights (R6, verified) ----
// grid (ceil(NN/64), 2): blockIdx.y = 0 -> xl (Wl), 1 -> xr (Wr).
// Output written in PERMUTED channel layout -> one half8 store per row.
template <typename TIN>
__global__ __launch_bounds__(256) void node_linear_mfma_k(
    const TIN* __restrict__ x, const _Float16* __restrict__ wtg,
    const float* __restrict__ bl, const float* __restrict__ br,
    _Float16* __restrict__ xl16, _Float16* __restrict__ xr16) {
  __shared__ _Float16 wt[128 * 128];  // 32 KB
  const int tid = threadIdx.x;
  const int which = blockIdx.y;
  const _Float16* wsrc = wtg + which * (128 * 128);
  const float* bias128 = which ? br : bl;
  _Float16* out = which ? xr16 : xl16;
  {
    const half8_t* src = (const half8_t*)wsrc;
    half8_t* dstl = (half8_t*)wt;
#pragma unroll
    for (int it = 0; it < 8; ++it)
      dstl[it * 256 + tid] = src[it * 256 + tid];
  }
  __syncthreads();

  const int wv = tid >> 6, lane = tid & 63;
  const int arow = lane & 15, kq = lane >> 4;
  const int nbase = blockIdx.x * 64 + wv * 16;
  int nload = nbase + arow;
  if (nload >= NN) nload = NN - 1;
  floatx4 acc[8];
#pragma unroll
  for (int t = 0; t < 8; ++t) acc[t] = (floatx4){0.f, 0.f, 0.f, 0.f};
#pragma unroll
  for (int kb = 0; kb < 4; ++kb) {
    const half8_t a = load_a8(x + (size_t)nload * 128 + kb * 32 + kq * 8);
    const int colbase = (kb * 32 + kq * 8) ^ ((arow & 7) << 3);
#pragma unroll
    for (int t = 0; t < 8; ++t) {
      const half8_t b = *(const half8_t*)&wt[(t * 16 + arow) * 128 + colbase];
      acc[t] = __builtin_amdgcn_mfma_f32_16x16x32_f16(a, b, acc[t], 0, 0, 0);
    }
  }
  float bv[8];
#pragma unroll
  for (int t = 0; t < 8; ++t) bv[t] = bias128[t * 16 + arow];
#pragma unroll
  for (int i = 0; i < 4; ++i) {
    const int n = nbase + kq * 4 + i;
    if (n < NN) {
      half8_t v;
#pragma unroll
      for (int t = 0; t < 8; ++t) v[t] = (_Float16)(acc[t][i] + bv[t]);
      *(half8_t*)(out + (size_t)n * 128 + arow * 8) = v;
    }
  }
}

// ---- build: in-edge CSR (src,eidx int2) + fp16 edge-attr copy ----
__global__ void build_k(const int* __restrict__ src, const int* __restrict__ dst,
                        const float* __restrict__ eattr,
                        int* __restrict__ cnt, int2* __restrict__ bpair,
                        _Float16* __restrict__ eatt16) {
  const int e = blockIdx.x * blockDim.x + threadIdx.x;
  if (e >= NE) return;
  const float4* ea = (const float4*)(eattr + (size_t)e * FEAT_E);
  const float4 a0 = ea[0], a1 = ea[1], a2 = ea[2], a3 = ea[3];
  half8_t h0 = {(_Float16)a0.x, (_Float16)a0.y, (_Float16)a0.z, (_Float16)a0.w,
                (_Float16)a1.x, (_Float16)a1.y, (_Float16)a1.z, (_Float16)a1.w};
  half8_t h1 = {(_Float16)a2.x, (_Float16)a2.y, (_Float16)a2.z, (_Float16)a2.w,
                (_Float16)a3.x, (_Float16)a3.y, (_Float16)a3.z, (_Float16)a3.w};
  half8_t* eo = (half8_t*)(eatt16 + (size_t)e * FEAT_E);
  eo[0] = h0; eo[1] = h1;
  const int d = dst[e];
  const int pos = atomicAdd(&cnt[d], 1);
  if (pos < CAP) bpair[(size_t)d * CAP + pos] = make_int2(src[e], e);
}

// ---- FUSED per-node GATv2 (R5 pair-unrolled body + multi-node waves) ----
// block 256 = 4 waves; each wave processes NPW nodes serially.
// Wave: 4 edge-slots (slot = lane>>4) x 16 lanes; lane owns 8 positions
// (= contiguous half8 of the permuted layout; channels 16j+l16, head j>>1).
// We in LDS (4 KB, keeps VGPR moderate; R4 showed the register version
// halves occupancy). No max-shift: logits O(1) at these weight scales;
// softmax shift-invariant (rounds 1-6 absmax 0.0).
__global__ __launch_bounds__(256) void node_gat_fused_k(
    const _Float16* __restrict__ xl16, const _Float16* __restrict__ xr16,
    const _Float16* __restrict__ eatt16,
    const int2* __restrict__ bpair, const int* __restrict__ cnt,
    const float* __restrict__ We, const float* __restrict__ att,
    const float* __restrict__ bias, _Float16* __restrict__ hout) {
  __shared__ half8_t WeS[FEAT_E][16];  // WeS[f][q][j] = We[f][16j+q], 4 KB
  const int tid = threadIdx.x;
  {
    const int f = tid >> 4, q = tid & 15;
    half8_t w;
#pragma unroll
    for (int j = 0; j < 8; ++j) w[j] = (_Float16)We[f * 128 + 16 * j + q];
    WeS[f][q] = w;
  }
  __syncthreads();

  const int wave = tid >> 6, lane = tid & 63;
  const int slot = lane >> 4, l16 = lane & 15;

  // att for lane's positions, packed per head: atp[h] = {att[32h+l16], att[32h+16+l16]}
  half2_t atp[4];
#pragma unroll
  for (int h = 0; h < 4; ++h)
    atp[h] = (half2_t){(_Float16)att[32 * h + l16], (_Float16)att[32 * h + 16 + l16]};
  float biasR[8];
#pragma unroll
  for (int j = 0; j < 8; ++j) biasR[j] = bias[16 * j + l16];

  const int dbase = (blockIdx.x * 4 + wave) * NPW;
  for (int ni = 0; ni < NPW; ++ni) {
    const int d = dbase + ni;
    if (d >= NN) break;
    int deg = cnt[d];
    deg = deg < CAP ? deg : CAP;
    const int2* bp = bpair + (size_t)d * CAP;
    const half8_t xrh = *(const half8_t*)(xr16 + (size_t)d * 128 + l16 * 8);

    float acc0 = 0.f, acc1 = 0.f, acc2 = 0.f, acc3 = 0.f;
    float acc4 = 0.f, acc5 = 0.f, acc6 = 0.f, acc7 = 0.f;
    float den0 = 0.f, den1 = 0.f, den2 = 0.f, den3 = 0.f;

#define FINISH_EDGE(XL, EM)                                               \
    {                                                                     \
      half8_t m_ = ((XL) + xrh) + (EM);                                   \
      half8_t lk_ = hmax8(m_, m_ * splat8((_Float16)0.2f));               \
      float p0_ = fdot2h((half2_t){lk_[0], lk_[1]}, atp[0], 0.f);         \
      float p1_ = fdot2h((half2_t){lk_[2], lk_[3]}, atp[1], 0.f);         \
      float p2_ = fdot2h((half2_t){lk_[4], lk_[5]}, atp[2], 0.f);         \
      float p3_ = fdot2h((half2_t){lk_[6], lk_[7]}, atp[3], 0.f);         \
      half2_t q01_ = {(_Float16)p0_, (_Float16)p1_};                      \
      half2_t q23_ = {(_Float16)p2_, (_Float16)p3_};                      \
      q01_ += h2shfl_xor(q01_, 1);  q23_ += h2shfl_xor(q23_, 1);          \
      q01_ += h2shfl_xor(q01_, 2);  q23_ += h2shfl_xor(q23_, 2);          \
      q01_ += h2shfl_xor(q01_, 4);  q23_ += h2shfl_xor(q23_, 4);          \
      q01_ += h2shfl_xor(q01_, 8);  q23_ += h2shfl_xor(q23_, 8);          \
      const float w0_ = __expf((float)q01_[0]);                           \
      const float w1_ = __expf((float)q01_[1]);                           \
      const float w2_ = __expf((float)q23_[0]);                           \
      const float w3_ = __expf((float)q23_[1]);                           \
      den0 += w0_; den1 += w1_; den2 += w2_; den3 += w3_;                 \
      acc0 = fmaf(w0_, (float)(XL)[0], acc0);                             \
      acc1 = fmaf(w0_, (float)(XL)[1], acc1);                             \
      acc2 = fmaf(w1_, (float)(XL)[2], acc2);                             \
      acc3 = fmaf(w1_, (float)(XL)[3], acc3);                             \
      acc4 = fmaf(w2_, (float)(XL)[4], acc4);                             \
      acc5 = fmaf(w2_, (float)(XL)[5], acc5);                             \
      acc6 = fmaf(w3_, (float)(XL)[6], acc6);                             \
      acc7 = fmaf(w3_, (float)(XL)[7], acc7);                             \
    }

    int j = slot;
    for (; j + 4 < deg; j += 8) {
      const int2 p0 = bp[j];
      const int2 p1 = bp[j + 4];
      const half8_t x0 = *(const half8_t*)(xl16 + (unsigned)p0.x * 128u + l16 * 8);
      const half8_t x1 = *(const half8_t*)(xl16 + (unsigned)p1.x * 128u + l16 * 8);
      const half8_t a0 = *(const half8_t*)(eatt16 + (unsigned)p0.y * 16u);
      const half8_t b0 = *(const half8_t*)(eatt16 + (unsigned)p0.y * 16u + 8u);
      const half8_t a1 = *(const half8_t*)(eatt16 + (unsigned)p1.y * 16u);
      const half8_t b1 = *(const half8_t*)(eatt16 + (unsigned)p1.y * 16u + 8u);
      half8_t em0 = {}, em1 = {};
#pragma unroll
      for (int f = 0; f < 8; ++f) {
        const half8_t wf = WeS[f][l16];  // shared by the pair
        em0 += splat8(a0[f]) * wf;
        em1 += splat8(a1[f]) * wf;
      }
#pragma unroll
      for (int f = 0; f < 8; ++f) {
        const half8_t wf = WeS[8 + f][l16];
        em0 += splat8(b0[f]) * wf;
        em1 += splat8(b1[f]) * wf;
      }
      FINISH_EDGE(x0, em0)
      FINISH_EDGE(x1, em1)
    }
    if (j < deg) {  // tail: at most one entry per slot remains
      const int2 p0 = bp[j];
      const half8_t x0 = *(const half8_t*)(xl16 + (unsigned)p0.x * 128u + l16 * 8);
      const half8_t a0 = *(const half8_t*)(eatt16 + (unsigned)p0.y * 16u);
      const half8_t b0 = *(const half8_t*)(eatt16 + (unsigned)p0.y * 16u + 8u);
      half8_t em0 = {};
#pragma unroll
      for (int f = 0; f < 8; ++f) em0 += splat8(a0[f]) * WeS[f][l16];
#pragma unroll
      for (int f = 0; f < 8; ++f) em0 += splat8(b0[f]) * WeS[8 + f][l16];
      FINISH_EDGE(x0, em0)
    }
#undef FINISH_EDGE

    // combine the 4 slots
#define RED(A) A += __shfl_xor(A, 16); A += __shfl_xor(A, 32);
    RED(acc0) RED(acc1) RED(acc2) RED(acc3)
    RED(acc4) RED(acc5) RED(acc6) RED(acc7)
    RED(den0) RED(den1) RED(den2) RED(den3)
#undef RED
    if (slot == 0) {
      const float i0 = 1.f / (den0 + 1e-16f);
      const float i1 = 1.f / (den1 + 1e-16f);
      const float i2 = 1.f / (den2 + 1e-16f);
      const float i3 = 1.f / (den3 + 1e-16f);
      float o0 = fmaf(acc0, i0, biasR[0]), o1 = fmaf(acc1, i0, biasR[1]);
      float o2 = fmaf(acc2, i1, biasR[2]), o3 = fmaf(acc3, i1, biasR[3]);
      float o4 = fmaf(acc4, i2, biasR[4]), o5 = fmaf(acc5, i2, biasR[5]);
      float o6 = fmaf(acc6, i3, biasR[6]), o7 = fmaf(acc7, i3, biasR[7]);
      o0 = o0 > 0.f ? o0 : expm1f(o0);  o1 = o1 > 0.f ? o1 : expm1f(o1);
      o2 = o2 > 0.f ? o2 : expm1f(o2);  o3 = o3 > 0.f ? o3 : expm1f(o3);
      o4 = o4 > 0.f ? o4 : expm1f(o4);  o5 = o5 > 0.f ? o5 : expm1f(o5);
      o6 = o6 > 0.f ? o6 : expm1f(o6);  o7 = o7 > 0.f ? o7 : expm1f(o7);
      half8_t ho = {(_Float16)o0, (_Float16)o1, (_Float16)o2, (_Float16)o3,
                    (_Float16)o4, (_Float16)o5, (_Float16)o6, (_Float16)o7};
      *(half8_t*)(hout + (size_t)d * 128 + l16 * 8) = ho;  // permuted layout
    }
  }
}

// ---- graph pooling (fp16 h, permuted layout -> map position to channel) ----
__global__ void pool_k(const _Float16* __restrict__ h, const int* __restrict__ batch,
                       float* __restrict__ gsum, unsigned int* __restrict__ gmax,
                       float* __restrict__ gcnt) {
  __shared__ float ssum[NGRAPH][HIDD];
  __shared__ float smax[NGRAPH][HIDD];
  __shared__ float scnt[NGRAPH];
  const int t = threadIdx.x;
  const int cmap = 16 * (t & 7) + (t >> 3);  // original channel of position t
#pragma unroll
  for (int g = 0; g < NGRAPH; ++g) {
    ssum[g][t] = 0.f;
    smax[g][t] = -3.0e38f;
  }
  if (t < NGRAPH) scnt[t] = 0.f;
  __syncthreads();
  const int n0 = blockIdx.x * 64;
  const int nEnd = (n0 + 64 < NN) ? (n0 + 64) : NN;
  unsigned int seen = 0;
  for (int n = n0; n < nEnd; ++n) {
    const int g = batch[n];
    seen |= 1u << g;
    const float v = (float)h[(size_t)n * HIDD + t];
    ssum[g][t] += v;
    smax[g][t] = fmaxf(smax[g][t], v);
    if (t == 0) scnt[g] += 1.f;
  }
  __syncthreads();
  for (int g = 0; g < NGRAPH; ++g) {
    if (seen & (1u << g)) {
      atomicAdd(&gsum[g * HIDD + cmap], ssum[g][t]);
      atomicMax(&gmax[g * HIDD + cmap], fenc(smax[g][t]));
      if (t == 0) atomicAdd(&gcnt[g], scnt[g]);
    }
  }
}

// ---- FC head (original channel space) ----
__global__ void head_k(const float* __restrict__ suma, const unsigned int* __restrict__ maxa,
                       const float* __restrict__ cnta,
                       const float* __restrict__ sumb, const unsigned int* __restrict__ maxb,
                       const float* __restrict__ cntb,
                       const float* __restrict__ Wf1, const float* __restrict__ bf1,
                       const float* __restrict__ Wf2, const float* __restrict__ bf2,
                       float* __restrict__ out) {
  __shared__ float c[4 * HIDD];
  __shared__ float red[HIDD];
  const int g = blockIdx.x, t = threadIdx.x;  // 128 threads
  const float ca = fmaxf(cnta[g], 1.f), cb = fmaxf(cntb[g], 1.f);
  c[t]            = suma[g * HIDD + t] / ca;
  c[HIDD + t]     = fdec(maxa[g * HIDD + t]);
  c[2 * HIDD + t] = sumb[g * HIDD + t] / cb;
  c[3 * HIDD + t] = fdec(maxb[g * HIDD + t]);
  __syncthreads();
  float acc = bf1[t];
  for (int i = 0; i < 4 * HIDD; ++i)
    acc = fmaf(c[i], Wf1[(size_t)i * HIDD + t], acc);
  acc = fmaxf(acc, 0.f);
  red[t] = acc * Wf2[t];
  __syncthreads();
  for (int s2 = 64; s2 > 0; s2 >>= 1) {
    if (t < s2) red[t] += red[t + s2];
    __syncthreads();
  }
  if (t == 0) out[g] = 1.f / (1.f + expf(-(red[0] + bf2[0])));
}

extern "C" void kernel_launch(void* const* d_in, const int* in_sizes, int n_in,
                              void* d_out, int out_size, void* d_ws, size_t ws_size,
                              hipStream_t stream) {
  (void)in_sizes; (void)n_in; (void)out_size; (void)ws_size;
  const float* xA    = (const float*)d_in[0];
  const int*   eiA   = (const int*)  d_in[1];
  const float* eaA   = (const float*)d_in[2];
  const int*   batA  = (const int*)  d_in[3];
  const float* xB    = (const float*)d_in[4];
  const int*   eiB   = (const int*)  d_in[5];
  const float* eaB   = (const float*)d_in[6];
  const int*   batB  = (const int*)  d_in[7];
  const float* W1l   = (const float*)d_in[8];
  const float* b1l   = (const float*)d_in[9];
  const float* W1r   = (const float*)d_in[10];
  const float* b1r   = (const float*)d_in[11];
  const float* W1e   = (const float*)d_in[12];
  const float* att1  = (const float*)d_in[13];
  const float* bias1 = (const float*)d_in[14];
  const float* W2l   = (const float*)d_in[15];
  const float* b2l   = (const float*)d_in[16];
  const float* W2r   = (const float*)d_in[17];
  const float* b2r   = (const float*)d_in[18];
  const float* W2e   = (const float*)d_in[19];
  const float* att2  = (const float*)d_in[20];
  const float* bias2 = (const float*)d_in[21];
  const float* Wf1   = (const float*)d_in[22];
  const float* bf1   = (const float*)d_in[23];
  const float* Wf2   = (const float*)d_in[24];
  const float* bf2   = (const float*)d_in[25];

  char* ws = (char*)d_ws;
  size_t off = 0;
  auto alloc = [&](size_t bytes) -> void* {
    void* p = ws + off;
    off += (bytes + 255) & ~(size_t)255;
    return p;
  };
  _Float16* h16    = (_Float16*)alloc((size_t)NN * HIDD * 2);
  _Float16* xl16   = (_Float16*)alloc((size_t)NN * HIDD * 2);
  _Float16* xr16   = (_Float16*)alloc((size_t)NN * HIDD * 2);
  int2*     bpair  = (int2*)    alloc((size_t)NN * CAP * 8);
  _Float16* eatt16 = (_Float16*)alloc((size_t)NE * FEAT_E * 2);
  int*      cnt    = (int*)     alloc((size_t)NN * 4);
  _Float16* wtg1   = (_Float16*)alloc(2 * 128 * 128 * 2);
  _Float16* wtg2   = (_Float16*)alloc(2 * 128 * 128 * 2);
  const size_t poolStart = off;
  float*        psumA = (float*)alloc(NGRAPH * HIDD * 4);
  unsigned int* pmaxA = (unsigned int*)alloc(NGRAPH * HIDD * 4);
  float*        pcntA = (float*)alloc(NGRAPH * 4);
  float*        psumB = (float*)alloc(NGRAPH * HIDD * 4);
  unsigned int* pmaxB = (unsigned int*)alloc(NGRAPH * HIDD * 4);
  float*        pcntB = (float*)alloc(NGRAPH * 4);
  const size_t poolBytes = off - poolStart;

  const float* xs[2]   = {xA, xB};
  const int*   eis[2]  = {eiA, eiB};
  const float* eas[2]  = {eaA, eaB};
  const int*   bats[2] = {batA, batB};
  float*        psums[2] = {psumA, psumB};
  unsigned int* pmaxs[2] = {pmaxA, pmaxB};
  float*        pcnts[2] = {pcntA, pcntB};

  hipMemsetAsync(psumA, 0, poolBytes, stream);  // 0 == encoded -inf for max
  prep_wt_k<<<256, 128, 0, stream>>>(W1l, W1r, wtg1, 0);  // layer 1: no perm
  prep_wt_k<<<256, 128, 0, stream>>>(W2l, W2r, wtg2, 1);  // layer 2: k-perm

  const int fusedGrid = (NN + 4 * NPW - 1) / (4 * NPW);
  for (int g = 0; g < 2; ++g) {
    const int* src = eis[g];
    const int* dst = eis[g] + NE;
    hipMemsetAsync(cnt, 0, (size_t)NN * 4, stream);
    build_k<<<NE / 256, 256, 0, stream>>>(src, dst, eas[g], cnt, bpair, eatt16);
    // layer 1 (fp32 x input, standard layout)
    node_linear_mfma_k<float><<<dim3((NN + 63) / 64, 2), 256, 0, stream>>>(
        xs[g], wtg1, b1l, b1r, xl16, xr16);
    node_gat_fused_k<<<fusedGrid, 256, 0, stream>>>(xl16, xr16, eatt16, bpair, cnt,
                                                    W1e, att1, bias1, h16);
    // layer 2 (fp16 h input, permuted layout matched by wtg2 row-perm)
    node_linear_mfma_k<_Float16><<<dim3((NN + 63) / 64, 2), 256, 0, stream>>>(
        h16, wtg2, b2l, b2r, xl16, xr16);
    node_gat_fused_k<<<fusedGrid, 256, 0, stream>>>(xl16, xr16, eatt16, bpair, cnt,
                                                    W2e, att2, bias2, h16);
    // pooling (permuted h -> channel map inside)
    pool_k<<<(NN + 63) / 64, 128, 0, stream>>>(h16, bats[g], psums[g], pmaxs[g], pcnts[g]);
  }
  head_k<<<NGRAPH, 128, 0, stream>>>(psumA, pmaxA, pcntA, psumB, pmaxB, pcntB,
                                     Wf1, bf1, Wf2, bf2, (float*)d_out);
}

// Round 8
// 853.901 us; speedup vs baseline: 1.3925x; 1.0885x over previous
//
#include <hip/hip_runtime.h>
#include <hip/hip_fp16.h>

#define NN 50000
#define NE 800000
#define HIDD 128
#define FEAT_E 16
#define NGRAPH 8
#define CAP 64

typedef __attribute__((ext_vector_type(2))) _Float16 half2_t;
typedef __attribute__((ext_vector_type(8))) _Float16 half8_t;
typedef __attribute__((ext_vector_type(4))) float floatx4;

// Layout note: node_linear's MFMA epilogue computes, for tile t and lane
// arow, output channel oc(t,arow) = arow*8 + t (set by column-ordering the
// staged weight matrix wtg). Lane arow therefore holds channels
// [arow*8, arow*8+8) contiguously -> ONE half8 store in STANDARD layout,
// and the fused kernel's lane l16 owns 8 contiguous same-head channels
// (head = l16>>2). No permutation anywhere else in the pipeline.

// ---- order-preserving float<->uint encoding for atomicMax on floats ----
__device__ __forceinline__ unsigned int fenc(float f) {
  unsigned int u = __float_as_uint(f);
  return (u & 0x80000000u) ? ~u : (u | 0x80000000u);
}
__device__ __forceinline__ float fdec(unsigned int u) {
  if (u == 0u) return 0.0f;
  float f = (u & 0x80000000u) ? __uint_as_float(u & 0x7fffffffu)
                              : __uint_as_float(~u);
  return __builtin_isfinite(f) ? f : 0.0f;
}

__device__ __forceinline__ half8_t splat8(_Float16 v) {
  return (half8_t){v, v, v, v, v, v, v, v};
}
__device__ __forceinline__ half8_t hmax8(half8_t a, half8_t b) {
#if __has_builtin(__builtin_elementwise_max)
  return __builtin_elementwise_max(a, b);
#else
  half8_t r;
#pragma unroll
  for (int i = 0; i < 8; ++i) r[i] = a[i] > b[i] ? a[i] : b[i];
  return r;
#endif
}
__device__ __forceinline__ float dot_att(half8_t lk, half2_t t01, half2_t t23,
                                         half2_t t45, half2_t t67) {
#if __has_builtin(__builtin_amdgcn_fdot2)
  float p = __builtin_amdgcn_fdot2((half2_t){lk[0], lk[1]}, t01, 0.f, false);
  p = __builtin_amdgcn_fdot2((half2_t){lk[2], lk[3]}, t23, p, false);
  p = __builtin_amdgcn_fdot2((half2_t){lk[4], lk[5]}, t45, p, false);
  p = __builtin_amdgcn_fdot2((half2_t){lk[6], lk[7]}, t67, p, false);
  return p;
#else
  float p = 0.f;
  p += (float)lk[0] * (float)t01[0] + (float)lk[1] * (float)t01[1];
  p += (float)lk[2] * (float)t23[0] + (float)lk[3] * (float)t23[1];
  p += (float)lk[4] * (float)t45[0] + (float)lk[5] * (float)t45[1];
  p += (float)lk[6] * (float)t67[0] + (float)lk[7] * (float)t67[1];
  return p;
#endif
}

// ---- prep: wtg[which(2)][r(128)][col(128)] fp16, col = k ^ ((r&7)<<3).
// Row r of the staged matrix holds W[:, oc_src(r)] with
// oc_src(r) = (r&15)*8 + (r>>4)  -> identity output layout (see note above).
__global__ void prep_wt_k(const float* __restrict__ Wl, const float* __restrict__ Wr,
                          _Float16* __restrict__ wtg) {
  const int r = blockIdx.x & 127;
  const int which = blockIdx.x >> 7;
  const int k = threadIdx.x;  // 0..127
  const float* W = which ? Wr : Wl;
  const int oc_src = (r & 15) * 8 + (r >> 4);
  const int col = k ^ ((r & 7) << 3);
  wtg[(which * 128 + r) * 128 + col] = (_Float16)W[k * 128 + oc_src];
}

// ---- A-fragment loaders (fp32 input layer 1, fp16 layer 2) ----
__device__ __forceinline__ half8_t load_a8(const _Float16* p) {
  return *(const half8_t*)p;
}
__device__ __forceinline__ half8_t load_a8(const float* p) {
  const float4 f0 = *(const float4*)p;
  const float4 f1 = *(const float4*)(p + 4);
  return (half8_t){(_Float16)f0.x, (_Float16)f0.y, (_Float16)f0.z, (_Float16)f0.w,
                   (_Float16)f1.x, (_Float16)f1.y, (_Float16)f1.z, (_Float16)f1.w};
}

// ---- node linear via MFMA, LDS-staged swizzled weights ----
// grid (ceil(NN/64), 2): blockIdx.y = 0 -> xl (Wl), 1 -> xr (Wr).
// block 256 = 4 waves; wave = 16 nodes x 128 outs (8 tiles, 32 acc VGPR).
// Epilogue: lane arow stores channels [arow*8, arow*8+8) as one half8.
template <typename TIN>
__global__ __launch_bounds__(256) void node_linear_mfma_k(
    const TIN* __restrict__ x, const _Float16* __restrict__ wtg,
    const float* __restrict__ bl, const float* __restrict__ br,
    _Float16* __restrict__ xl16, _Float16* __restrict__ xr16) {
  __shared__ _Float16 wt[128 * 128];  // 32 KB
  const int tid = threadIdx.x;
  const int which = blockIdx.y;
  const _Float16* wsrc = wtg + which * (128 * 128);
  const float* bias128 = which ? br : bl;
  _Float16* out = which ? xr16 : xl16;
  {
    const half8_t* src = (const half8_t*)wsrc;
    half8_t* dstl = (half8_t*)wt;
#pragma unroll
    for (int it = 0; it < 8; ++it)
      dstl[it * 256 + tid] = src[it * 256 + tid];
  }
  __syncthreads();

  const int wv = tid >> 6, lane = tid & 63;
  const int arow = lane & 15, kq = lane >> 4;
  const int nbase = blockIdx.x * 64 + wv * 16;
  int nload = nbase + arow;
  if (nload >= NN) nload = NN - 1;
  floatx4 acc[8];
#pragma unroll
  for (int t = 0; t < 8; ++t) acc[t] = (floatx4){0.f, 0.f, 0.f, 0.f};
#pragma unroll
  for (int kb = 0; kb < 4; ++kb) {
    const half8_t a = load_a8(x + (size_t)nload * 128 + kb * 32 + kq * 8);
    const int colbase = (kb * 32 + kq * 8) ^ ((arow & 7) << 3);
#pragma unroll
    for (int t = 0; t < 8; ++t) {
      const half8_t b = *(const half8_t*)&wt[(t * 16 + arow) * 128 + colbase];
      acc[t] = __builtin_amdgcn_mfma_f32_16x16x32_f16(a, b, acc[t], 0, 0, 0);
    }
  }
  // lane arow, tile t -> channel arow*8+t; bias is 8 contiguous floats
  const float4 bv0 = *(const float4*)&bias128[arow * 8];
  const float4 bv1 = *(const float4*)&bias128[arow * 8 + 4];
  const float bv[8] = {bv0.x, bv0.y, bv0.z, bv0.w, bv1.x, bv1.y, bv1.z, bv1.w};
#pragma unroll
  for (int i = 0; i < 4; ++i) {
    const int n = nbase + kq * 4 + i;
    if (n < NN) {
      half8_t v;
#pragma unroll
      for (int t = 0; t < 8; ++t) v[t] = (_Float16)(acc[t][i] + bv[t]);
      *(half8_t*)(out + (size_t)n * 128 + arow * 8) = v;
    }
  }
}

// ---- build: in-edge CSR (src,eidx int2) + fp16 edge-attr copy ----
__global__ void build_k(const int* __restrict__ src, const int* __restrict__ dst,
                        const float* __restrict__ eattr,
                        int* __restrict__ cnt, int2* __restrict__ bpair,
                        _Float16* __restrict__ eatt16) {
  const int e = blockIdx.x * blockDim.x + threadIdx.x;
  if (e >= NE) return;
  const float4* ea = (const float4*)(eattr + (size_t)e * FEAT_E);
  const float4 a0 = ea[0], a1 = ea[1], a2 = ea[2], a3 = ea[3];
  half8_t h0 = {(_Float16)a0.x, (_Float16)a0.y, (_Float16)a0.z, (_Float16)a0.w,
                (_Float16)a1.x, (_Float16)a1.y, (_Float16)a1.z, (_Float16)a1.w};
  half8_t h1 = {(_Float16)a2.x, (_Float16)a2.y, (_Float16)a2.z, (_Float16)a2.w,
                (_Float16)a3.x, (_Float16)a3.y, (_Float16)a3.z, (_Float16)a3.w};
  half8_t* eo = (half8_t*)(eatt16 + (size_t)e * FEAT_E);
  eo[0] = h0; eo[1] = h1;
  const int d = dst[e];
  const int pos = atomicAdd(&cnt[d], 1);
  if (pos < CAP) bpair[(size_t)d * CAP + pos] = make_int2(src[e], e);
}

// ---- FUSED per-node GATv2 (R5 body, best measured: 123.6 us) ----
// block 256 = 4 waves, one wave per destination node (grid = NN/4).
// Wave: 4 edge-slots (slot = lane>>4) x 16 lanes; lane owns 8 contiguous
// channels (head = l16>>2, single head per lane). We in LDS (4 KB; R4
// showed the register version halves occupancy). Pair-unrolled: 2
// independent gather chains; WeS reads shared by the pair. No max-shift:
// logits O(1) at these weight scales; softmax shift-invariant (absmax 0.0
// rounds 1-7).
__global__ __launch_bounds__(256) void node_gat_fused_k(
    const _Float16* __restrict__ xl16, const _Float16* __restrict__ xr16,
    const _Float16* __restrict__ eatt16,
    const int2* __restrict__ bpair, const int* __restrict__ cnt,
    const float* __restrict__ We, const float* __restrict__ att,
    const float* __restrict__ bias, _Float16* __restrict__ hout) {
  __shared__ half8_t WeS[FEAT_E][16];  // WeS[f][q] = We[f][8q..8q+7], 4 KB
  const int tid = threadIdx.x;
  {
    const int f = tid >> 4, q = tid & 15;
    const float4 w0 = ((const float4*)We)[f * 32 + q * 2];
    const float4 w1 = ((const float4*)We)[f * 32 + q * 2 + 1];
    WeS[f][q] = (half8_t){(_Float16)w0.x, (_Float16)w0.y, (_Float16)w0.z, (_Float16)w0.w,
                          (_Float16)w1.x, (_Float16)w1.y, (_Float16)w1.z, (_Float16)w1.w};
  }
  __syncthreads();

  const int wave = tid >> 6, lane = tid & 63;
  const int slot = lane >> 4, l16 = lane & 15;
  const int d = blockIdx.x * 4 + wave;  // grid = NN/4 exactly

  const float4 af0 = ((const float4*)att)[l16 * 2];
  const float4 af1 = ((const float4*)att)[l16 * 2 + 1];
  const half2_t at01 = {(_Float16)af0.x, (_Float16)af0.y};
  const half2_t at23 = {(_Float16)af0.z, (_Float16)af0.w};
  const half2_t at45 = {(_Float16)af1.x, (_Float16)af1.y};
  const half2_t at67 = {(_Float16)af1.z, (_Float16)af1.w};

  const half8_t xrh = *(const half8_t*)(xr16 + (size_t)d * HIDD + l16 * 8);

  int deg = cnt[d];
  deg = deg < CAP ? deg : CAP;
  const int2* bp = bpair + (size_t)d * CAP;

  float acc0 = 0.f, acc1 = 0.f, acc2 = 0.f, acc3 = 0.f;
  float acc4 = 0.f, acc5 = 0.f, acc6 = 0.f, acc7 = 0.f;
  float den = 0.f;

#define FINISH_EDGE(XL, EM)                                              \
  {                                                                      \
    half8_t m_ = ((XL) + xrh) + (EM);                                    \
    half8_t lk_ = hmax8(m_, m_ * splat8((_Float16)0.2f));                \
    float p_ = dot_att(lk_, at01, at23, at45, at67);                     \
    p_ += __shfl_xor(p_, 1);                                             \
    p_ += __shfl_xor(p_, 2);                                             \
    const float w_ = __expf(p_);                                         \
    den += w_;                                                           \
    acc0 = fmaf(w_, (float)(XL)[0], acc0);                               \
    acc1 = fmaf(w_, (float)(XL)[1], acc1);                               \
    acc2 = fmaf(w_, (float)(XL)[2], acc2);                               \
    acc3 = fmaf(w_, (float)(XL)[3], acc3);                               \
    acc4 = fmaf(w_, (float)(XL)[4], acc4);                               \
    acc5 = fmaf(w_, (float)(XL)[5], acc5);                               \
    acc6 = fmaf(w_, (float)(XL)[6], acc6);                               \
    acc7 = fmaf(w_, (float)(XL)[7], acc7);                               \
  }

  int j = slot;
  for (; j + 4 < deg; j += 8) {
    const int2 p0 = bp[j];
    const int2 p1 = bp[j + 4];
    const half8_t x0 = *(const half8_t*)(xl16 + (unsigned)p0.x * 128u + l16 * 8);
    const half8_t x1 = *(const half8_t*)(xl16 + (unsigned)p1.x * 128u + l16 * 8);
    const half8_t a0 = *(const half8_t*)(eatt16 + (unsigned)p0.y * 16u);
    const half8_t b0 = *(const half8_t*)(eatt16 + (unsigned)p0.y * 16u + 8u);
    const half8_t a1 = *(const half8_t*)(eatt16 + (unsigned)p1.y * 16u);
    const half8_t b1 = *(const half8_t*)(eatt16 + (unsigned)p1.y * 16u + 8u);
    half8_t em0 = {}, em1 = {};
#pragma unroll
    for (int f = 0; f < 8; ++f) {
      const half8_t wf = WeS[f][l16];  // shared by the pair
      em0 += splat8(a0[f]) * wf;
      em1 += splat8(a1[f]) * wf;
    }
#pragma unroll
    for (int f = 0; f < 8; ++f) {
      const half8_t wf = WeS[8 + f][l16];
      em0 += splat8(b0[f]) * wf;
      em1 += splat8(b1[f]) * wf;
    }
    FINISH_EDGE(x0, em0)
    FINISH_EDGE(x1, em1)
  }
  if (j < deg) {  // tail: at most one entry per slot remains
    const int2 p0 = bp[j];
    const half8_t x0 = *(const half8_t*)(xl16 + (unsigned)p0.x * 128u + l16 * 8);
    const half8_t a0 = *(const half8_t*)(eatt16 + (unsigned)p0.y * 16u);
    const half8_t b0 = *(const half8_t*)(eatt16 + (unsigned)p0.y * 16u + 8u);
    half8_t em0 = {};
#pragma unroll
    for (int f = 0; f < 8; ++f) em0 += splat8(a0[f]) * WeS[f][l16];
#pragma unroll
    for (int f = 0; f < 8; ++f) em0 += splat8(b0[f]) * WeS[8 + f][l16];
    FINISH_EDGE(x0, em0)
  }
#undef FINISH_EDGE

  // combine 4 slots
#define RED(A) A += __shfl_xor(A, 16); A += __shfl_xor(A, 32);
  RED(acc0) RED(acc1) RED(acc2) RED(acc3)
  RED(acc4) RED(acc5) RED(acc6) RED(acc7)
  RED(den)
#undef RED
  if (slot == 0) {
    const float inv = 1.f / (den + 1e-16f);
    const float4 b0 = ((const float4*)bias)[l16 * 2];
    const float4 b1 = ((const float4*)bias)[l16 * 2 + 1];
    float o0 = fmaf(acc0, inv, b0.x), o1 = fmaf(acc1, inv, b0.y);
    float o2 = fmaf(acc2, inv, b0.z), o3 = fmaf(acc3, inv, b0.w);
    float o4 = fmaf(acc4, inv, b1.x), o5 = fmaf(acc5, inv, b1.y);
    float o6 = fmaf(acc6, inv, b1.z), o7 = fmaf(acc7, inv, b1.w);
    o0 = o0 > 0.f ? o0 : expm1f(o0);  o1 = o1 > 0.f ? o1 : expm1f(o1);
    o2 = o2 > 0.f ? o2 : expm1f(o2);  o3 = o3 > 0.f ? o3 : expm1f(o3);
    o4 = o4 > 0.f ? o4 : expm1f(o4);  o5 = o5 > 0.f ? o5 : expm1f(o5);
    o6 = o6 > 0.f ? o6 : expm1f(o6);  o7 = o7 > 0.f ? o7 : expm1f(o7);
    half8_t ho = {(_Float16)o0, (_Float16)o1, (_Float16)o2, (_Float16)o3,
                  (_Float16)o4, (_Float16)o5, (_Float16)o6, (_Float16)o7};
    *(half8_t*)(hout + (size_t)d * HIDD + l16 * 8) = ho;
  }
}

// ---- graph pooling (fp16 h, standard layout) ----
__global__ void pool_k(const _Float16* __restrict__ h, const int* __restrict__ batch,
                       float* __restrict__ gsum, unsigned int* __restrict__ gmax,
                       float* __restrict__ gcnt) {
  __shared__ float ssum[NGRAPH][HIDD];
  __shared__ float smax[NGRAPH][HIDD];
  __shared__ float scnt[NGRAPH];
  const int t = threadIdx.x;
#pragma unroll
  for (int g = 0; g < NGRAPH; ++g) {
    ssum[g][t] = 0.f;
    smax[g][t] = -3.0e38f;
  }
  if (t < NGRAPH) scnt[t] = 0.f;
  __syncthreads();
  const int n0 = blockIdx.x * 64;
  const int nEnd = (n0 + 64 < NN) ? (n0 + 64) : NN;
  unsigned int seen = 0;
  for (int n = n0; n < nEnd; ++n) {
    const int g = batch[n];
    seen |= 1u << g;
    const float v = (float)h[(size_t)n * HIDD + t];
    ssum[g][t] += v;
    smax[g][t] = fmaxf(smax[g][t], v);
    if (t == 0) scnt[g] += 1.f;
  }
  __syncthreads();
  for (int g = 0; g < NGRAPH; ++g) {
    if (seen & (1u << g)) {
      atomicAdd(&gsum[g * HIDD + t], ssum[g][t]);
      atomicMax(&gmax[g * HIDD + t], fenc(smax[g][t]));
      if (t == 0) atomicAdd(&gcnt[g], scnt[g]);
    }
  }
}

// ---- FC head ----
__global__ void head_k(const float* __restrict__ suma, const unsigned int* __restrict__ maxa,
                       const float* __restrict__ cnta,
                       const float* __restrict__ sumb, const unsigned int* __restrict__ maxb,
                       const float* __restrict__ cntb,
                       const float* __restrict__ Wf1, const float* __restrict__ bf1,
                       const float* __restrict__ Wf2, const float* __restrict__ bf2,
                       float* __restrict__ out) {
  __shared__ float c[4 * HIDD];
  __shared__ float red[HIDD];
  const int g = blockIdx.x, t = threadIdx.x;  // 128 threads
  const float ca = fmaxf(cnta[g], 1.f), cb = fmaxf(cntb[g], 1.f);
  c[t]            = suma[g * HIDD + t] / ca;
  c[HIDD + t]     = fdec(maxa[g * HIDD + t]);
  c[2 * HIDD + t] = sumb[g * HIDD + t] / cb;
  c[3 * HIDD + t] = fdec(maxb[g * HIDD + t]);
  __syncthreads();
  float acc = bf1[t];
  for (int i = 0; i < 4 * HIDD; ++i)
    acc = fmaf(c[i], Wf1[(size_t)i * HIDD + t], acc);
  acc = fmaxf(acc, 0.f);
  red[t] = acc * Wf2[t];
  __syncthreads();
  for (int s2 = 64; s2 > 0; s2 >>= 1) {
    if (t < s2) red[t] += red[t + s2];
    __syncthreads();
  }
  if (t == 0) out[g] = 1.f / (1.f + expf(-(red[0] + bf2[0])));
}

extern "C" void kernel_launch(void* const* d_in, const int* in_sizes, int n_in,
                              void* d_out, int out_size, void* d_ws, size_t ws_size,
                              hipStream_t stream) {
  (void)in_sizes; (void)n_in; (void)out_size; (void)ws_size;
  const float* xA    = (const float*)d_in[0];
  const int*   eiA   = (const int*)  d_in[1];
  const float* eaA   = (const float*)d_in[2];
  const int*   batA  = (const int*)  d_in[3];
  const float* xB    = (const float*)d_in[4];
  const int*   eiB   = (const int*)  d_in[5];
  const float* eaB   = (const float*)d_in[6];
  const int*   batB  = (const int*)  d_in[7];
  const float* W1l   = (const float*)d_in[8];
  const float* b1l   = (const float*)d_in[9];
  const float* W1r   = (const float*)d_in[10];
  const float* b1r   = (const float*)d_in[11];
  const float* W1e   = (const float*)d_in[12];
  const float* att1  = (const float*)d_in[13];
  const float* bias1 = (const float*)d_in[14];
  const float* W2l   = (const float*)d_in[15];
  const float* b2l   = (const float*)d_in[16];
  const float* W2r   = (const float*)d_in[17];
  const float* b2r   = (const float*)d_in[18];
  const float* W2e   = (const float*)d_in[19];
  const float* att2  = (const float*)d_in[20];
  const float* bias2 = (const float*)d_in[21];
  const float* Wf1   = (const float*)d_in[22];
  const float* bf1   = (const float*)d_in[23];
  const float* Wf2   = (const float*)d_in[24];
  const float* bf2   = (const float*)d_in[25];

  char* ws = (char*)d_ws;
  size_t off = 0;
  auto alloc = [&](size_t bytes) -> void* {
    void* p = ws + off;
    off += (bytes + 255) & ~(size_t)255;
    return p;
  };
  _Float16* h16    = (_Float16*)alloc((size_t)NN * HIDD * 2);
  _Float16* xl16   = (_Float16*)alloc((size_t)NN * HIDD * 2);
  _Float16* xr16   = (_Float16*)alloc((size_t)NN * HIDD * 2);
  int2*     bpair  = (int2*)    alloc((size_t)NN * CAP * 8);
  _Float16* eatt16 = (_Float16*)alloc((size_t)NE * FEAT_E * 2);
  int*      cnt    = (int*)     alloc((size_t)NN * 4);
  _Float16* wtg1   = (_Float16*)alloc(2 * 128 * 128 * 2);
  _Float16* wtg2   = (_Float16*)alloc(2 * 128 * 128 * 2);
  const size_t poolStart = off;
  float*        psumA = (float*)alloc(NGRAPH * HIDD * 4);
  unsigned int* pmaxA = (unsigned int*)alloc(NGRAPH * HIDD * 4);
  float*        pcntA = (float*)alloc(NGRAPH * 4);
  float*        psumB = (float*)alloc(NGRAPH * HIDD * 4);
  unsigned int* pmaxB = (unsigned int*)alloc(NGRAPH * HIDD * 4);
  float*        pcntB = (float*)alloc(NGRAPH * 4);
  const size_t poolBytes = off - poolStart;

  const float* xs[2]   = {xA, xB};
  const int*   eis[2]  = {eiA, eiB};
  const float* eas[2]  = {eaA, eaB};
  const int*   bats[2] = {batA, batB};
  float*        psums[2] = {psumA, psumB};
  unsigned int* pmaxs[2] = {pmaxA, pmaxB};
  float*        pcnts[2] = {pcntA, pcntB};

  hipMemsetAsync(psumA, 0, poolBytes, stream);  // 0 == encoded -inf for max
  prep_wt_k<<<256, 128, 0, stream>>>(W1l, W1r, wtg1);
  prep_wt_k<<<256, 128, 0, stream>>>(W2l, W2r, wtg2);

  for (int g = 0; g < 2; ++g) {
    const int* src = eis[g];
    const int* dst = eis[g] + NE;
    hipMemsetAsync(cnt, 0, (size_t)NN * 4, stream);
    build_k<<<NE / 256, 256, 0, stream>>>(src, dst, eas[g], cnt, bpair, eatt16);
    // layer 1 (fp32 x input)
    node_linear_mfma_k<float><<<dim3((NN + 63) / 64, 2), 256, 0, stream>>>(
        xs[g], wtg1, b1l, b1r, xl16, xr16);
    node_gat_fused_k<<<NN / 4, 256, 0, stream>>>(xl16, xr16, eatt16, bpair, cnt,
                                                 W1e, att1, bias1, h16);
    // layer 2 (fp16 h input, standard layout)
    node_linear_mfma_k<_Float16><<<dim3((NN + 63) / 64, 2), 256, 0, stream>>>(
        h16, wtg2, b2l, b2r, xl16, xr16);
    node_gat_fused_k<<<NN / 4, 256, 0, stream>>>(xl16, xr16, eatt16, bpair, cnt,
                                                 W2e, att2, bias2, h16);
    // pooling
    pool_k<<<(NN + 63) / 64, 128, 0, stream>>>(h16, bats[g], psums[g], pmaxs[g], pcnts[g]);
  }
  head_k<<<NGRAPH, 128, 0, stream>>>(psumA, pmaxA, pcntA, psumB, pmaxB, pcntB,
                                     Wf1, bf1, Wf2, bf2, (float*)d_out);
}